// Round 10
// baseline (2035.501 us; speedup 1.0000x reference)
//
#include <hip/hip_runtime.h>
#include <hip/hip_fp16.h>

// Many2OneRNN: B=64, S=4096, I=256, H=256, O=128
// Fused heterogeneous kernel, chunked over time (T_C=1024, 4 chunks):
//   blocks 0..63   : recurrence for chunk c   (1 block/chain, 1024 thr)
//   blocks 64..    : xp GEMM for chunk c+1    (128 t-rows/block, MFMA f16)
// xp double-buffered in d_ws so launch i overlaps rnn(i-1) with xp(i).
// R10: recurrence math moved from v_dot2_f32_f16 (suspected quarter-rate;
//   R4-R9 wall fits 8 cyc/inst) to v_fma_f32 (HW-verified 2 cyc, m07):
//   a-state kept as f32 in LDS [16][20] (80 B stride: 16-lane b128 = 2-way
//   bank = free), Waa rows as 64 f32 VGPRs, 64 fma/thread/step.
// rnn per thread/step: 4 ds_read_b128 (broadcast), 64 v_fma_f32,
//   5-DPP quad_perm+row_ror rotate-reduce, 5-op tanh, predicated ds_write.
// Phase 3 (out = sigmoid(Wya*a + Wya_b)) folded into the last rnn launch.

typedef _Float16 f16x8 __attribute__((ext_vector_type(8)));
typedef _Float16 f16x4 __attribute__((ext_vector_type(4)));
typedef float    f32x4 __attribute__((ext_vector_type(4)));

// row_ror:D within 16 lanes: dst lane i gets src lane (i-D)&15
template <int D>
__device__ __forceinline__ float rorf(float v) {
    return __builtin_bit_cast(float,
        __builtin_amdgcn_update_dpp(0, __builtin_bit_cast(int, v),
                                    0x120 + D, 0xF, 0xF, true));
}
// quad_perm rotate within 4 lanes: dst j gets src (j-D)&3
template <int D>
__device__ __forceinline__ float qrot(float v) {
    constexpr int ctrl = D == 1 ? 0x93 : (D == 2 ? 0x4E : 0x39);
    return __builtin_bit_cast(float,
        __builtin_amdgcn_update_dpp(0, __builtin_bit_cast(int, v),
                                    ctrl, 0xF, 0xF, true));
}

__global__ __launch_bounds__(1024)
__attribute__((amdgpu_waves_per_eu(4, 4)))
void k_fused(
    const float* __restrict__ x, const float* __restrict__ Ww,
    const float* __restrict__ Wb, const float* __restrict__ Waa,
    const float* __restrict__ Wab, const float* __restrict__ Wya,
    const float* __restrict__ Wyb, float* __restrict__ out,
    _Float16* __restrict__ xp0, _Float16* __restrict__ xp1,
    float* __restrict__ a_state,
    int c_rnn, int c_xp, int do_rnn, int do_xp, int is_last,
    int T_C, int logT)
{
    // LDS: xp path uses As (67.5 KB); rnn path uses aL/afin (3.5 KB).
    __shared__ __align__(16) _Float16 As[128 * 264];
    __shared__ __align__(16) float aL[2][16][20];   // [buf][chunk][16 f32 + 4 pad]
    __shared__ float afin[256];

    const int tid  = threadIdx.x;
    const int lane = tid & 63;

    if (blockIdx.x < 64) {
        // ================= RNN path =================
        if (!do_rnn) return;
        const _Float16* xp = (c_rnn & 1) ? xp1 : xp0;
        const int w     = tid >> 6;      // 0..15
        const int k     = lane & 15;     // K-slice [k*16, k*16+16)
        const int g     = lane >> 4;     // 0..3
        const int rbase = w * 16 + g * 4;
        const int myrow = rbase + (k & 3);
        const int b     = blockIdx.x;
        const bool wlane = (k & 12) == 0;

        // weights f32: slot i -> row rbase+((k+i)&3), K-contiguous (64 VGPR)
        float wr[4][16];
#pragma unroll
        for (int i = 0; i < 4; ++i) {
            const float4* wp = (const float4*)(Waa + (size_t)(rbase + ((k + i) & 3)) * 256 + k * 16);
#pragma unroll
            for (int q = 0; q < 4; ++q) {
                float4 v = wp[q];
                wr[i][4 * q + 0] = v.x; wr[i][4 * q + 1] = v.y;
                wr[i][4 * q + 2] = v.z; wr[i][4 * q + 3] = v.w;
            }
        }
        const float bias = Wab[myrow];

        if (tid < 256) {
            aL[0][tid >> 4][tid & 15] = (c_rnn == 0) ? 0.f : a_state[b * 256 + tid];
        }
        __syncthreads();

        const _Float16* xph = xp + ((size_t)(b * 256 + myrow)) * T_C;
        f16x8 xq = *(const f16x8*)(xph);
        float bx[8];
#pragma unroll
        for (int j = 0; j < 8; ++j) bx[j] = bias + (float)xq[j];

        const float* rp0 = &aL[0][k][0];
        const float* rp1 = &aL[1][k][0];
        float* wq0 = &aL[1][w][g * 4 + k];  // wlane only (k<4)
        float* wq1 = &aL[0][w][g * 4 + k];

#define RNN_STEP(J, FIN)                                                     \
    {                                                                        \
        const float* rp = ((J) & 1) ? rp1 : rp0;                             \
        float4 av0 = *(const float4*)(rp);                                   \
        float4 av1 = *(const float4*)(rp + 4);                               \
        float4 av2 = *(const float4*)(rp + 8);                               \
        float4 av3 = *(const float4*)(rp + 12);                              \
        float av[16] = {av0.x, av0.y, av0.z, av0.w,                          \
                        av1.x, av1.y, av1.z, av1.w,                          \
                        av2.x, av2.y, av2.z, av2.w,                          \
                        av3.x, av3.y, av3.z, av3.w};                         \
        float s0 = 0.f, s1 = 0.f, s2 = 0.f, s3 = 0.f;                        \
        _Pragma("unroll")                                                    \
        for (int q = 0; q < 16; ++q) {                                       \
            s0 = fmaf(wr[0][q], av[q], s0);                                  \
            s1 = fmaf(wr[1][q], av[q], s1);                                  \
            s2 = fmaf(wr[2][q], av[q], s2);                                  \
            s3 = fmaf(wr[3][q], av[q], s3);                                  \
        }                                                                    \
        /* 5-DPP reduce: quad rotate-reduce then fold the 4 quads */         \
        float t = s0 + qrot<1>(s1);                                          \
        t += qrot<2>(s2);                                                    \
        t += qrot<3>(s3);                                                    \
        float u   = t + rorf<4>(t);                                          \
        float acc = u + rorf<8>(u);                                          \
        float z  = bx[(J)] + acc;                                            \
        float e2 = __expf(2.f * z);                                          \
        float a  = fmaf(-2.f, __builtin_amdgcn_rcpf(e2 + 1.f), 1.f);         \
        if (wlane) *(((J) & 1) ? wq1 : wq0) = a;                             \
        if (FIN) {                                                           \
            afin[myrow] = a;                                                 \
            a_state[b * 256 + myrow] = a;                                    \
        }                                                                    \
        asm volatile("s_waitcnt lgkmcnt(0)" ::: "memory");                   \
        __builtin_amdgcn_s_barrier();                                        \
        asm volatile("" ::: "memory");                                       \
    }

        for (int tb = 0; tb + 8 < T_C; tb += 8) {
            f16x8 xn = *(const f16x8*)(xph + tb + 8);
            RNN_STEP(0, false) RNN_STEP(1, false) RNN_STEP(2, false) RNN_STEP(3, false)
            RNN_STEP(4, false) RNN_STEP(5, false) RNN_STEP(6, false) RNN_STEP(7, false)
#pragma unroll
            for (int j = 0; j < 8; ++j) bx[j] = bias + (float)xn[j];
        }
        RNN_STEP(0, false) RNN_STEP(1, false) RNN_STEP(2, false) RNN_STEP(3, false)
        RNN_STEP(4, false) RNN_STEP(5, false) RNN_STEP(6, false) RNN_STEP(7, true)
#undef RNN_STEP

        if (is_last) {
            const int o  = tid >> 3;   // 0..127
            const int k8 = tid & 7;
            const float4* wp = (const float4*)(Wya + (size_t)o * 256 + k8 * 32);
            const float4* ap = (const float4*)(afin + k8 * 32);
            float s = 0.f;
#pragma unroll
            for (int i = 0; i < 8; ++i) {
                float4 wv4 = wp[i];
                float4 a4  = ap[i];
                s += wv4.x * a4.x + wv4.y * a4.y + wv4.z * a4.z + wv4.w * a4.w;
            }
            s += __shfl_xor(s, 1);
            s += __shfl_xor(s, 2);
            s += __shfl_xor(s, 4);
            if (k8 == 0)
                out[b * 128 + o] = __builtin_amdgcn_rcpf(1.f + __expf(-(s + Wyb[o])));
        }
    } else {
        // ================= XP path (chunk c_xp, 128 t-rows/block) =========
        if (!do_xp) return;
        _Float16* xp = (c_xp & 1) ? xp1 : xp0;
        const int bxp = blockIdx.x - 64;
        const int wv  = tid >> 6;    // 0..15
        const int l15 = lane & 15;
        const int lk  = lane >> 4;   // 0..3
        const int n0  = wv * 16;

        // B fragments: Wax_w rows n0+l15 (16 cols per wave), K-contiguous
        f16x8 bfr[8];
        {
            const float* wrow = Ww + (size_t)(n0 + l15) * 256;
#pragma unroll
            for (int kt = 0; kt < 8; ++kt) {
                const float4* wp = (const float4*)(wrow + kt * 32 + lk * 8);
                float4 v0 = wp[0], v1 = wp[1];
                f16x8 f;
                f[0] = (_Float16)v0.x; f[1] = (_Float16)v0.y;
                f[2] = (_Float16)v0.z; f[3] = (_Float16)v0.w;
                f[4] = (_Float16)v1.x; f[5] = (_Float16)v1.y;
                f[6] = (_Float16)v1.z; f[7] = (_Float16)v1.w;
                bfr[kt] = f;
            }
        }
        const float bias = Wb[n0 + l15];

        // stage A tile (128 rows x 256 K) f32 -> f16 LDS
        {
            const int arow = tid >> 3;           // 0..127
            const int acol = (tid & 7) * 32;     // 0..224
            const int r    = bxp * 128 + arow;
            const int bb   = r >> logT;
            const int tl   = r & (T_C - 1);
            const float4* s4 = (const float4*)(x + ((size_t)(bb * 4096 + c_xp * T_C + tl) << 8) + acol);
            _Float16* d = As + arow * 264 + acol;
#pragma unroll
            for (int q = 0; q < 4; ++q) {
                float4 v0 = s4[2 * q], v1 = s4[2 * q + 1];
                f16x8 p;
                p[0] = (_Float16)v0.x; p[1] = (_Float16)v0.y;
                p[2] = (_Float16)v0.z; p[3] = (_Float16)v0.w;
                p[4] = (_Float16)v1.x; p[5] = (_Float16)v1.y;
                p[6] = (_Float16)v1.z; p[7] = (_Float16)v1.w;
                *(f16x8*)(d + q * 8) = p;
            }
        }
        __syncthreads();

        f32x4 acc[8] = {};
#pragma unroll
        for (int kt = 0; kt < 8; ++kt) {
#pragma unroll
            for (int mt = 0; mt < 8; ++mt) {
                f16x8 af = *(const f16x8*)(As + (mt * 16 + l15) * 264 + kt * 32 + lk * 8);
                acc[mt] = __builtin_amdgcn_mfma_f32_16x16x32_f16(af, bfr[kt], acc[mt], 0, 0, 0);
            }
        }

        // store xp3[b][h][t]: 4 t-contiguous halves per 8B store
        const int base = bxp * 128;
#pragma unroll
        for (int mt = 0; mt < 8; ++mt) {
            const int rr  = base + mt * 16 + lk * 4;
            const int bb2 = rr >> logT;
            const int tt  = rr & (T_C - 1);
            f16x4 pk;
#pragma unroll
            for (int r2 = 0; r2 < 4; ++r2) pk[r2] = (_Float16)(acc[mt][r2] + bias);
            *(f16x4*)(xp + ((size_t)(bb2 * 256 + n0 + l15)) * T_C + tt) = pk;
        }
    }
}

// ---------------------------------------------------------------------------
extern "C" void kernel_launch(void* const* d_in, const int* in_sizes, int n_in,
                              void* d_out, int out_size, void* d_ws, size_t ws_size,
                              hipStream_t stream)
{
    (void)in_sizes; (void)n_in; (void)out_size;
    const float* x    = (const float*)d_in[0];
    const float* Waxw = (const float*)d_in[1];
    const float* Waxb = (const float*)d_in[2];
    const float* Waaw = (const float*)d_in[3];
    const float* Waab = (const float*)d_in[4];
    const float* Wyaw = (const float*)d_in[5];
    const float* Wyab = (const float*)d_in[6];
    float* out = (float*)d_out;

    // chunk size: T_C=1024 (4 chunks) for xp/rnn overlap; shrink to fit ws
    // (needs 2 xp chunk buffers + 64KB f32 state).
    int T_C = 1024, logT = 10;
    while (T_C > 128 && (size_t)2 * 64 * T_C * 256 * 2 + 131072 > ws_size) { T_C >>= 1; --logT; }

    _Float16* xp0 = (_Float16*)d_ws;
    _Float16* xp1 = xp0 + (size_t)64 * T_C * 256;
    float* a_state = (float*)(xp1 + (size_t)64 * T_C * 256);

    const int nc  = 4096 / T_C;
    const int nxp = 64 * T_C / 128;   // xp blocks per chunk
    for (int i = 0; i <= nc; ++i) {
        // launch i: rnn on chunk i-1 (if any) overlapped with xp on chunk i
        k_fused<<<dim3(64 + nxp), dim3(1024), 0, stream>>>(
            x, Waxw, Waxb, Waaw, Waab, Wyaw, Wyab, out, xp0, xp1, a_state,
            i - 1, i, i >= 1 ? 1 : 0, i < nc ? 1 : 0, i == nc ? 1 : 0,
            T_C, logT);
    }
}